// Round 1
// baseline (5812.515 us; speedup 1.0000x reference)
//
#include <hip/hip_runtime.h>

#define H 128

__device__ __forceinline__ int lower_bound_i(const int* __restrict__ a, int n, int v) {
    int lo = 0, hi = n;
    while (lo < hi) { int m = (lo + hi) >> 1; if (a[m] < v) lo = m + 1; else hi = m; }
    return lo;
}

// deg[dst] += 1 for each edge (self-loop handled as +1 in dis_kernel)
__global__ void deg_kernel(const int* __restrict__ ei, int E, float* __restrict__ deg) {
    int e = blockIdx.x * blockDim.x + threadIdx.x;
    if (e < E) atomicAdd(&deg[ei[E + e]], 1.0f);
}

// in-place: deg -> rsqrt(deg + 1)   (deg+1 >= 1 so max(deg,1) is implicit)
__global__ void dis_kernel(float* __restrict__ deg, int N) {
    int i = blockIdx.x * blockDim.x + threadIdx.x;
    if (i < N) deg[i] = rsqrtf(deg[i] + 1.0f);
}

// h1 = x @ W1   (N x 6) @ (6 x 128)
__global__ void mm1_kernel(const float* __restrict__ x, const float* __restrict__ W1,
                           float* __restrict__ h1, int N) {
    __shared__ float w[6 * H];
    for (int i = threadIdx.x; i < 6 * H; i += blockDim.x) w[i] = W1[i];
    __syncthreads();
    int idx = blockIdx.x * blockDim.x + threadIdx.x;
    int n = idx >> 7, f = idx & 127;
    if (n < N) {
        const float* xr = x + (long long)n * 6;
        float acc = 0.f;
        #pragma unroll
        for (int k = 0; k < 6; ++k) acc += xr[k] * w[k * H + f];
        h1[idx] = acc;
    }
}

// agg[dst] += dis[src]*dis[dst] * h[src]   -- 32 lanes per edge, float4 each
__global__ void scatter_kernel(const int* __restrict__ ei, int E,
                               const float* __restrict__ dis,
                               const float* __restrict__ h,
                               float* __restrict__ agg) {
    long long t = (long long)blockIdx.x * blockDim.x + threadIdx.x;
    int e = (int)(t >> 5);
    if (e >= E) return;
    int lane = (int)(t & 31);
    int s = ei[e], d = ei[E + e];
    float nrm = dis[s] * dis[d];
    float4 v = *(const float4*)(h + (long long)s * H + lane * 4);
    float* out = agg + (long long)d * H + lane * 4;
    atomicAdd(out + 0, v.x * nrm);
    atomicAdd(out + 1, v.y * nrm);
    atomicAdd(out + 2, v.z * nrm);
    atomicAdd(out + 3, v.w * nrm);
}

// agg[i] += dis[i]^2 * h[i]  (self-loops; runs after scatter, no atomics needed)
__global__ void selfloop_kernel(const float* __restrict__ dis, const float* __restrict__ h,
                                float* __restrict__ agg, int N) {
    int idx = blockIdx.x * blockDim.x + threadIdx.x;
    int n = idx >> 7;
    if (n < N) {
        float dd = dis[n] * dis[n];
        agg[idx] += dd * h[idx];
    }
}

// h2 = relu(agg1 + b1) @ W2   (N x 128) @ (128 x 128), W2 staged in LDS in 2 K-halves
#define MM2_NODES 32
__global__ __launch_bounds__(256) void mm2_kernel(const float* __restrict__ agg1,
                                                  const float* __restrict__ b1,
                                                  const float* __restrict__ W2,
                                                  float* __restrict__ h2, int N) {
    __shared__ float w[64 * H];   // 32 KB: one K-half of W2
    __shared__ float a[2][64];
    int f = threadIdx.x & 127;
    int half = threadIdx.x >> 7;   // 0..1, which node of the pair
    int base = blockIdx.x * MM2_NODES;
    float acc[MM2_NODES / 2];
    #pragma unroll
    for (int i = 0; i < MM2_NODES / 2; ++i) acc[i] = 0.f;

    for (int kh = 0; kh < 2; ++kh) {
        __syncthreads();  // protect w from overwrite while prior reads in flight
        for (int i = threadIdx.x; i < 64 * H; i += 256) w[i] = W2[kh * 64 * H + i];
        __syncthreads();
        for (int it = 0; it < MM2_NODES / 2; ++it) {
            int n = base + it * 2 + half;
            if (f < 64) {
                float av = 0.f;
                if (n < N) av = fmaxf(agg1[(long long)n * H + kh * 64 + f] + b1[kh * 64 + f], 0.f);
                a[half][f] = av;
            }
            __syncthreads();
            if (n < N) {
                float s = 0.f;
                #pragma unroll 16
                for (int k = 0; k < 64; ++k) s += a[half][k] * w[k * H + f];
                acc[it] += s;
            }
            __syncthreads();
        }
    }
    for (int it = 0; it < MM2_NODES / 2; ++it) {
        int n = base + it * 2 + half;
        if (n < N) h2[(long long)n * H + f] = acc[it];
    }
}

// out[g] = mean over nodes of agg2 + b2 ; batch is sorted so each graph is a range
__global__ void pool_kernel(const float* __restrict__ agg2, const int* __restrict__ batch,
                            const float* __restrict__ b2, float* __restrict__ out,
                            int N, int G) {
    __shared__ int s_start, s_end;
    int g = blockIdx.x;
    if (threadIdx.x == 0) {
        s_start = lower_bound_i(batch, N, g);
        s_end   = lower_bound_i(batch, N, g + 1);
    }
    __syncthreads();
    int start = s_start, end = s_end;
    int f = threadIdx.x;
    float acc = 0.f;
    for (int n = start; n < end; ++n) acc += agg2[(long long)n * H + f];
    int cnt = end - start;
    out[(long long)g * H + f] = (cnt > 0) ? (acc / (float)cnt + b2[f]) : 0.f;
}

extern "C" void kernel_launch(void* const* d_in, const int* in_sizes, int n_in,
                              void* d_out, int out_size, void* d_ws, size_t ws_size,
                              hipStream_t stream) {
    const float* x   = (const float*)d_in[0];
    const int*   ei  = (const int*)d_in[1];
    const int*   bat = (const int*)d_in[2];
    const float* W1  = (const float*)d_in[4];
    const float* b1  = (const float*)d_in[5];
    const float* W2  = (const float*)d_in[6];
    const float* b2  = (const float*)d_in[7];
    float* out = (float*)d_out;

    int N = in_sizes[0] / 6;
    int E = in_sizes[1] / 2;
    int G = out_size / H;

    char* ws = (char*)d_ws;
    size_t off = 0;
    float* dis  = (float*)(ws + off); off += (((size_t)N * 4) + 255) & ~(size_t)255;
    float* bufA = (float*)(ws + off); off += (((size_t)N * H * 4) + 255) & ~(size_t)255;
    float* bufB = (float*)(ws + off);

    // degrees -> dis
    hipMemsetAsync(dis, 0, (size_t)N * 4, stream);
    deg_kernel<<<(E + 255) / 256, 256, 0, stream>>>(ei, E, dis);
    dis_kernel<<<(N + 255) / 256, 256, 0, stream>>>(dis, N);

    // layer 1: h1 = x@W1 -> bufA ; aggregate -> bufB
    mm1_kernel<<<((long long)N * H + 255) / 256, 256, 0, stream>>>(x, W1, bufA, N);
    hipMemsetAsync(bufB, 0, (size_t)N * H * 4, stream);
    {
        long long tt = (long long)E * 32;
        scatter_kernel<<<(tt + 255) / 256, 256, 0, stream>>>(ei, E, dis, bufA, bufB);
    }
    selfloop_kernel<<<((long long)N * H + 255) / 256, 256, 0, stream>>>(dis, bufA, bufB, N);

    // layer 2: h2 = relu(bufB + b1) @ W2 -> bufA ; aggregate -> bufB
    mm2_kernel<<<(N + MM2_NODES - 1) / MM2_NODES, 256, 0, stream>>>(bufB, b1, W2, bufA, N);
    hipMemsetAsync(bufB, 0, (size_t)N * H * 4, stream);
    {
        long long tt = (long long)E * 32;
        scatter_kernel<<<(tt + 255) / 256, 256, 0, stream>>>(ei, E, dis, bufA, bufB);
    }
    selfloop_kernel<<<((long long)N * H + 255) / 256, 256, 0, stream>>>(dis, bufA, bufB, N);

    // pool (adds b2; empty graph -> 0)
    pool_kernel<<<G, H, 0, stream>>>(bufB, bat, b2, out, N, G);
}

// Round 2
// 1020.864 us; speedup vs baseline: 5.6937x; 5.6937x over previous
//
#include <hip/hip_runtime.h>

#define H 128

__device__ __forceinline__ int lower_bound_i(const int* __restrict__ a, int n, int v) {
    int lo = 0, hi = n;
    while (lo < hi) { int m = (lo + hi) >> 1; if (a[m] < v) lo = m + 1; else hi = m; }
    return lo;
}

// ---- degree / dis ----
__global__ void deg_kernel(const int* __restrict__ ei, int E, int* __restrict__ cnt) {
    int e = blockIdx.x * blockDim.x + threadIdx.x;
    if (e < E) atomicAdd(&cnt[ei[E + e]], 1);
}

__global__ void dis_kernel(const int* __restrict__ cnt, float* __restrict__ dis, int N) {
    int i = blockIdx.x * blockDim.x + threadIdx.x;
    if (i < N) dis[i] = rsqrtf((float)cnt[i] + 1.0f);   // +1 self-loop; deg+1 >= 1
}

// ---- prefix scan (counting sort by dst): 1024 elems / block ----
__global__ __launch_bounds__(256) void scan_block_sums(const int* __restrict__ cnt, int N,
                                                       int* __restrict__ bsum) {
    __shared__ int s[256];
    int b = blockIdx.x, t = threadIdx.x;
    int idx0 = b * 1024 + t * 4;
    int v = 0;
    #pragma unroll
    for (int j = 0; j < 4; ++j) if (idx0 + j < N) v += cnt[idx0 + j];
    s[t] = v;
    __syncthreads();
    for (int off = 128; off > 0; off >>= 1) {
        if (t < off) s[t] += s[t + off];
        __syncthreads();
    }
    if (t == 0) bsum[b] = s[0];
}

__global__ __launch_bounds__(1024) void scan_top(const int* __restrict__ bsum, int nb,
                                                 int* __restrict__ bbase,
                                                 int* __restrict__ rowptr, int N, int E) {
    __shared__ int s[1024];
    int t = threadIdx.x;
    int own = (t < nb) ? bsum[t] : 0;
    s[t] = own;
    __syncthreads();
    for (int off = 1; off < 1024; off <<= 1) {
        int v = (t >= off) ? s[t - off] : 0;
        __syncthreads();
        s[t] += v;
        __syncthreads();
    }
    if (t < nb) bbase[t] = s[t] - own;   // exclusive
    if (t == 0) rowptr[N] = E;
}

__global__ __launch_bounds__(256) void scan_write(const int* __restrict__ cnt, int N,
                                                  const int* __restrict__ bbase,
                                                  int* __restrict__ rowptr,
                                                  int* __restrict__ woff) {
    __shared__ int s[256];
    int b = blockIdx.x, t = threadIdx.x;
    int idx0 = b * 1024 + t * 4;
    int v[4];
    int tot = 0;
    #pragma unroll
    for (int j = 0; j < 4; ++j) { v[j] = (idx0 + j < N) ? cnt[idx0 + j] : 0; tot += v[j]; }
    s[t] = tot;
    __syncthreads();
    for (int off = 1; off < 256; off <<= 1) {
        int u = (t >= off) ? s[t - off] : 0;
        __syncthreads();
        s[t] += u;
        __syncthreads();
    }
    int p = bbase[b] + s[t] - tot;   // exclusive within block + block base
    #pragma unroll
    for (int j = 0; j < 4; ++j) {
        if (idx0 + j < N) { rowptr[idx0 + j] = p; woff[idx0 + j] = p; p += v[j]; }
    }
}

__global__ void fill_kernel(const int* __restrict__ ei, int E,
                            int* __restrict__ woff, int* __restrict__ csr_src) {
    int e = blockIdx.x * blockDim.x + threadIdx.x;
    if (e < E) {
        int s = ei[e], d = ei[E + e];
        int pos = atomicAdd(&woff[d], 1);
        csr_src[pos] = s;
    }
}

// ---- hs1 = dis[n] * (x @ W1)   (N x 6) @ (6 x 128) ----
__global__ void mm1_kernel(const float* __restrict__ x, const float* __restrict__ W1,
                           const float* __restrict__ dis, float* __restrict__ hs1, int N) {
    __shared__ float w[6 * H];
    for (int i = threadIdx.x; i < 6 * H; i += blockDim.x) w[i] = W1[i];
    __syncthreads();
    int idx = blockIdx.x * blockDim.x + threadIdx.x;
    int n = idx >> 7, f = idx & 127;
    if (n < N) {
        const float* xr = x + (long long)n * 6;
        float acc = 0.f;
        #pragma unroll
        for (int k = 0; k < 6; ++k) acc += xr[k] * w[k * H + f];
        hs1[idx] = acc * dis[n];
    }
}

// ---- agg[d] = dis[d] * ( hs[d] + sum_{s in N(d)} hs[s] ) ; 2 nodes / 256-thr block ----
__global__ __launch_bounds__(256) void agg_kernel(const int* __restrict__ rowptr,
                                                  const int* __restrict__ csr_src,
                                                  const float* __restrict__ dis,
                                                  const float* __restrict__ hs,
                                                  float* __restrict__ out, int N) {
    int node = blockIdx.x * 2 + (threadIdx.x >> 7);
    int f = threadIdx.x & 127;
    if (node >= N) return;
    int j0 = rowptr[node], j1 = rowptr[node + 1];
    float acc = hs[(long long)node * H + f];           // self loop (dis[d]*h[d] scaled form)
    for (int j = j0; j < j1; ++j) {
        int s = csr_src[j];
        acc += hs[(long long)s * H + f];
    }
    out[(long long)node * H + f] = dis[node] * acc;
}

// ---- hs2 = dis[n] * ( relu(agg1 + b1) @ W2 )   (N x 128) @ (128 x 128) ----
#define MM2_NODES 32
__global__ __launch_bounds__(256) void mm2_kernel(const float* __restrict__ agg1,
                                                  const float* __restrict__ b1,
                                                  const float* __restrict__ W2,
                                                  const float* __restrict__ dis,
                                                  float* __restrict__ hs2, int N) {
    __shared__ float w[64 * H];   // 32 KB: one K-half of W2
    __shared__ float a[2][64];
    int f = threadIdx.x & 127;
    int half = threadIdx.x >> 7;
    int base = blockIdx.x * MM2_NODES;
    float acc[MM2_NODES / 2];
    #pragma unroll
    for (int i = 0; i < MM2_NODES / 2; ++i) acc[i] = 0.f;

    for (int kh = 0; kh < 2; ++kh) {
        __syncthreads();
        for (int i = threadIdx.x; i < 64 * H; i += 256) w[i] = W2[kh * 64 * H + i];
        __syncthreads();
        for (int it = 0; it < MM2_NODES / 2; ++it) {
            int n = base + it * 2 + half;
            if (f < 64) {
                float av = 0.f;
                if (n < N) av = fmaxf(agg1[(long long)n * H + kh * 64 + f] + b1[kh * 64 + f], 0.f);
                a[half][f] = av;
            }
            __syncthreads();
            if (n < N) {
                float s = 0.f;
                #pragma unroll 16
                for (int k = 0; k < 64; ++k) s += a[half][k] * w[k * H + f];
                acc[it] += s;
            }
            __syncthreads();
        }
    }
    for (int it = 0; it < MM2_NODES / 2; ++it) {
        int n = base + it * 2 + half;
        if (n < N) hs2[(long long)n * H + f] = acc[it] * dis[n];
    }
}

// ---- out[g] = mean(agg2 rows) + b2 ; batch sorted -> binary search range ----
__global__ void pool_kernel(const float* __restrict__ agg2, const int* __restrict__ batch,
                            const float* __restrict__ b2, float* __restrict__ out,
                            int N, int G) {
    __shared__ int s_start, s_end;
    int g = blockIdx.x;
    if (threadIdx.x == 0) {
        s_start = lower_bound_i(batch, N, g);
        s_end   = lower_bound_i(batch, N, g + 1);
    }
    __syncthreads();
    int start = s_start, end = s_end;
    int f = threadIdx.x;
    float acc = 0.f;
    for (int n = start; n < end; ++n) acc += agg2[(long long)n * H + f];
    int cnt = end - start;
    out[(long long)g * H + f] = (cnt > 0) ? (acc / (float)cnt + b2[f]) : 0.f;
}

extern "C" void kernel_launch(void* const* d_in, const int* in_sizes, int n_in,
                              void* d_out, int out_size, void* d_ws, size_t ws_size,
                              hipStream_t stream) {
    const float* x   = (const float*)d_in[0];
    const int*   ei  = (const int*)d_in[1];
    const int*   bat = (const int*)d_in[2];
    const float* W1  = (const float*)d_in[4];
    const float* b1  = (const float*)d_in[5];
    const float* W2  = (const float*)d_in[6];
    const float* b2  = (const float*)d_in[7];
    float* out = (float*)d_out;

    int N = in_sizes[0] / 6;
    int E = in_sizes[1] / 2;
    int G = out_size / H;

    int nb = (N + 1023) / 1024;           // scan blocks (<= 1024 supported)

    char* ws = (char*)d_ws;
    size_t off = 0;
    auto carve = [&](size_t bytes) { void* p = ws + off; off = (off + bytes + 255) & ~(size_t)255; return p; };
    int*   cnt    = (int*)  carve((size_t)N * 4);
    float* dis    = (float*)carve((size_t)N * 4);
    int*   rowptr = (int*)  carve((size_t)(N + 1) * 4);
    int*   woff   = (int*)  carve((size_t)N * 4);
    int*   bsum   = (int*)  carve((size_t)nb * 4);
    int*   bbase  = (int*)  carve((size_t)nb * 4);
    int*   csrs   = (int*)  carve((size_t)E * 4);
    float* bufA   = (float*)carve((size_t)N * H * 4);
    float* bufB   = (float*)carve((size_t)N * H * 4);

    // degrees -> dis, CSR
    hipMemsetAsync(cnt, 0, (size_t)N * 4, stream);
    deg_kernel<<<(E + 255) / 256, 256, 0, stream>>>(ei, E, cnt);
    dis_kernel<<<(N + 255) / 256, 256, 0, stream>>>(cnt, dis, N);
    scan_block_sums<<<nb, 256, 0, stream>>>(cnt, N, bsum);
    scan_top<<<1, 1024, 0, stream>>>(bsum, nb, bbase, rowptr, N, E);
    scan_write<<<nb, 256, 0, stream>>>(cnt, N, bbase, rowptr, woff);
    fill_kernel<<<(E + 255) / 256, 256, 0, stream>>>(ei, E, woff, csrs);

    // layer 1
    mm1_kernel<<<((long long)N * H + 255) / 256, 256, 0, stream>>>(x, W1, dis, bufA, N);
    agg_kernel<<<(N + 1) / 2, 256, 0, stream>>>(rowptr, csrs, dis, bufA, bufB, N);

    // layer 2
    mm2_kernel<<<(N + MM2_NODES - 1) / MM2_NODES, 256, 0, stream>>>(bufB, b1, W2, dis, bufA, N);
    agg_kernel<<<(N + 1) / 2, 256, 0, stream>>>(rowptr, csrs, dis, bufA, bufB, N);

    // pool (adds b2; empty graph -> 0)
    pool_kernel<<<G, H, 0, stream>>>(bufB, bat, b2, out, N, G);
}

// Round 3
// 582.454 us; speedup vs baseline: 9.9794x; 1.7527x over previous
//
#include <hip/hip_runtime.h>

#define H 128

__device__ __forceinline__ int lower_bound_i(const int* __restrict__ a, int n, int v) {
    int lo = 0, hi = n;
    while (lo < hi) { int m = (lo + hi) >> 1; if (a[m] < v) lo = m + 1; else hi = m; }
    return lo;
}

// ---- degree / dis ----
__global__ void deg_kernel(const int* __restrict__ ei, int E, int* __restrict__ cnt) {
    int e = blockIdx.x * blockDim.x + threadIdx.x;
    if (e < E) atomicAdd(&cnt[ei[E + e]], 1);
}

__global__ void dis_kernel(const int* __restrict__ cnt, float* __restrict__ dis, int N) {
    int i = blockIdx.x * blockDim.x + threadIdx.x;
    if (i < N) dis[i] = rsqrtf((float)cnt[i] + 1.0f);   // +1 self-loop; deg+1 >= 1
}

// ---- prefix scan (counting sort by dst): 1024 elems / block ----
__global__ __launch_bounds__(256) void scan_block_sums(const int* __restrict__ cnt, int N,
                                                       int* __restrict__ bsum) {
    __shared__ int s[256];
    int b = blockIdx.x, t = threadIdx.x;
    int idx0 = b * 1024 + t * 4;
    int v = 0;
    #pragma unroll
    for (int j = 0; j < 4; ++j) if (idx0 + j < N) v += cnt[idx0 + j];
    s[t] = v;
    __syncthreads();
    for (int off = 128; off > 0; off >>= 1) {
        if (t < off) s[t] += s[t + off];
        __syncthreads();
    }
    if (t == 0) bsum[b] = s[0];
}

__global__ __launch_bounds__(1024) void scan_top(const int* __restrict__ bsum, int nb,
                                                 int* __restrict__ bbase,
                                                 int* __restrict__ rowptr, int N, int E) {
    __shared__ int s[1024];
    int t = threadIdx.x;
    int own = (t < nb) ? bsum[t] : 0;
    s[t] = own;
    __syncthreads();
    for (int off = 1; off < 1024; off <<= 1) {
        int v = (t >= off) ? s[t - off] : 0;
        __syncthreads();
        s[t] += v;
        __syncthreads();
    }
    if (t < nb) bbase[t] = s[t] - own;   // exclusive
    if (t == 0) rowptr[N] = E;
}

__global__ __launch_bounds__(256) void scan_write(const int* __restrict__ cnt, int N,
                                                  const int* __restrict__ bbase,
                                                  int* __restrict__ rowptr,
                                                  int* __restrict__ woff) {
    __shared__ int s[256];
    int b = blockIdx.x, t = threadIdx.x;
    int idx0 = b * 1024 + t * 4;
    int v[4];
    int tot = 0;
    #pragma unroll
    for (int j = 0; j < 4; ++j) { v[j] = (idx0 + j < N) ? cnt[idx0 + j] : 0; tot += v[j]; }
    s[t] = tot;
    __syncthreads();
    for (int off = 1; off < 256; off <<= 1) {
        int u = (t >= off) ? s[t - off] : 0;
        __syncthreads();
        s[t] += u;
        __syncthreads();
    }
    int p = bbase[b] + s[t] - tot;
    #pragma unroll
    for (int j = 0; j < 4; ++j) {
        if (idx0 + j < N) { rowptr[idx0 + j] = p; woff[idx0 + j] = p; p += v[j]; }
    }
}

__global__ void fill_kernel(const int* __restrict__ ei, int E,
                            int* __restrict__ woff, int* __restrict__ csr_src) {
    int e = blockIdx.x * blockDim.x + threadIdx.x;
    if (e < E) {
        int s = ei[e], d = ei[E + e];
        int pos = atomicAdd(&woff[d], 1);
        csr_src[pos] = s;
    }
}

// ---- hs1 = dis[n] * (x @ W1)   (N x 6) @ (6 x 128) ----
__global__ void mm1_kernel(const float* __restrict__ x, const float* __restrict__ W1,
                           const float* __restrict__ dis, float* __restrict__ hs1, int N) {
    __shared__ float w[6 * H];
    for (int i = threadIdx.x; i < 6 * H; i += blockDim.x) w[i] = W1[i];
    __syncthreads();
    int idx = blockIdx.x * blockDim.x + threadIdx.x;
    int n = idx >> 7, f = idx & 127;
    if (n < N) {
        const float* xr = x + (long long)n * 6;
        float acc = 0.f;
        #pragma unroll
        for (int k = 0; k < 6; ++k) acc += xr[k] * w[k * H + f];
        hs1[idx] = acc * dis[n];
    }
}

// ---- agg[d] = dis[d]*(hs[d] + sum_{s in N(d)} hs[s]) ; 32 lanes/node, float4, unroll 4 ----
__global__ __launch_bounds__(256) void agg_kernel(const int* __restrict__ rowptr,
                                                  const int* __restrict__ csr_src,
                                                  const float* __restrict__ dis,
                                                  const float* __restrict__ hs,
                                                  float* __restrict__ out, int N) {
    int node = blockIdx.x * 8 + (threadIdx.x >> 5);
    if (node >= N) return;
    int c = threadIdx.x & 31;
    const float4* hs4 = (const float4*)hs;
    int j0 = rowptr[node], j1 = rowptr[node + 1];
    float4 acc = hs4[(long long)node * 32 + c];     // self loop
    int j = j0;
    for (; j + 4 <= j1; j += 4) {
        int s0 = csr_src[j], s1 = csr_src[j + 1], s2 = csr_src[j + 2], s3 = csr_src[j + 3];
        float4 v0 = hs4[(long long)s0 * 32 + c];
        float4 v1 = hs4[(long long)s1 * 32 + c];
        float4 v2 = hs4[(long long)s2 * 32 + c];
        float4 v3 = hs4[(long long)s3 * 32 + c];
        acc.x += (v0.x + v1.x) + (v2.x + v3.x);
        acc.y += (v0.y + v1.y) + (v2.y + v3.y);
        acc.z += (v0.z + v1.z) + (v2.z + v3.z);
        acc.w += (v0.w + v1.w) + (v2.w + v3.w);
    }
    for (; j < j1; ++j) {
        float4 v = hs4[(long long)csr_src[j] * 32 + c];
        acc.x += v.x; acc.y += v.y; acc.z += v.z; acc.w += v.w;
    }
    float dd = dis[node];
    float4 o; o.x = acc.x * dd; o.y = acc.y * dd; o.z = acc.z * dd; o.w = acc.w * dd;
    ((float4*)out)[(long long)node * 32 + c] = o;
}

// ---- hs2 = dis[n]*(relu(agg1+b1) @ W2) ; reg-tiled: 64n x 128f per block ----
__global__ __launch_bounds__(256) void mm2_kernel(const float* __restrict__ agg1,
                                                  const float* __restrict__ b1,
                                                  const float* __restrict__ W2,
                                                  const float* __restrict__ dis,
                                                  float* __restrict__ hs2, int N) {
    __shared__ float a_lds[16][65];     // [k][n], padded: conflict-free staging writes
    __shared__ float w_lds[16 * 128];   // [k][f] flat
    int f4 = threadIdx.x & 31;          // float4 column index
    int g  = threadIdx.x >> 5;          // node group 0..7
    int base = blockIdx.x * 64;
    float4 acc[8];
    #pragma unroll
    for (int r = 0; r < 8; ++r) acc[r] = make_float4(0.f, 0.f, 0.f, 0.f);

    for (int kc = 0; kc < 128; kc += 16) {
        __syncthreads();
        {
            int t = threadIdx.x;
            int n  = t >> 2;            // 0..63
            int kq = (t & 3) * 4;       // 0,4,8,12
            int gn = base + n;
            float4 av = make_float4(0.f, 0.f, 0.f, 0.f);
            if (gn < N) {
                av = *(const float4*)(agg1 + (long long)gn * H + kc + kq);
                const float4 bv = *(const float4*)(b1 + kc + kq);
                av.x = fmaxf(av.x + bv.x, 0.f);
                av.y = fmaxf(av.y + bv.y, 0.f);
                av.z = fmaxf(av.z + bv.z, 0.f);
                av.w = fmaxf(av.w + bv.w, 0.f);
            }
            a_lds[kq + 0][n] = av.x;
            a_lds[kq + 1][n] = av.y;
            a_lds[kq + 2][n] = av.z;
            a_lds[kq + 3][n] = av.w;
            // stage W chunk: 16x128 floats = 512 float4, 2 per thread
            const float4* W4 = (const float4*)(W2 + (long long)kc * H);
            float4* wl4 = (float4*)w_lds;
            wl4[t] = W4[t];
            wl4[t + 256] = W4[t + 256];
        }
        __syncthreads();
        #pragma unroll
        for (int k = 0; k < 16; ++k) {
            float4 wv = ((const float4*)(w_lds + k * H))[f4];
            #pragma unroll
            for (int r = 0; r < 8; ++r) {
                float av = a_lds[k][g * 8 + r];
                acc[r].x += av * wv.x;
                acc[r].y += av * wv.y;
                acc[r].z += av * wv.z;
                acc[r].w += av * wv.w;
            }
        }
    }
    #pragma unroll
    for (int r = 0; r < 8; ++r) {
        int n = base + g * 8 + r;
        if (n < N) {
            float dd = dis[n];
            float4 o = make_float4(acc[r].x * dd, acc[r].y * dd, acc[r].z * dd, acc[r].w * dd);
            ((float4*)hs2)[(long long)n * 32 + f4] = o;
        }
    }
}

// ---- out[g] = mean(agg2 rows) + b2 ; 32 lanes/graph, float4 ----
__global__ __launch_bounds__(128) void pool_kernel(const float* __restrict__ agg2,
                                                   const int* __restrict__ batch,
                                                   const float* __restrict__ b2,
                                                   float* __restrict__ out, int N, int G) {
    int g = blockIdx.x * 4 + (threadIdx.x >> 5);
    int c = threadIdx.x & 31;
    if (g >= G) return;
    int start = lower_bound_i(batch, N, g);
    int end   = lower_bound_i(batch, N, g + 1);
    const float4* a4 = (const float4*)agg2;
    float4 acc = make_float4(0.f, 0.f, 0.f, 0.f);
    for (int n = start; n < end; ++n) {
        float4 v = a4[(long long)n * 32 + c];
        acc.x += v.x; acc.y += v.y; acc.z += v.z; acc.w += v.w;
    }
    int cnt = end - start;
    float4 bv = ((const float4*)b2)[c];
    float4 o = make_float4(0.f, 0.f, 0.f, 0.f);
    if (cnt > 0) {
        float inv = 1.f / (float)cnt;
        o.x = acc.x * inv + bv.x; o.y = acc.y * inv + bv.y;
        o.z = acc.z * inv + bv.z; o.w = acc.w * inv + bv.w;
    }
    ((float4*)out)[(long long)g * 32 + c] = o;
}

extern "C" void kernel_launch(void* const* d_in, const int* in_sizes, int n_in,
                              void* d_out, int out_size, void* d_ws, size_t ws_size,
                              hipStream_t stream) {
    const float* x   = (const float*)d_in[0];
    const int*   ei  = (const int*)d_in[1];
    const int*   bat = (const int*)d_in[2];
    const float* W1  = (const float*)d_in[4];
    const float* b1  = (const float*)d_in[5];
    const float* W2  = (const float*)d_in[6];
    const float* b2  = (const float*)d_in[7];
    float* out = (float*)d_out;

    int N = in_sizes[0] / 6;
    int E = in_sizes[1] / 2;
    int G = out_size / H;

    int nb = (N + 1023) / 1024;

    char* ws = (char*)d_ws;
    size_t off = 0;
    auto carve = [&](size_t bytes) { void* p = ws + off; off = (off + bytes + 255) & ~(size_t)255; return p; };
    int*   cnt    = (int*)  carve((size_t)N * 4);
    float* dis    = (float*)carve((size_t)N * 4);
    int*   rowptr = (int*)  carve((size_t)(N + 1) * 4);
    int*   woff   = (int*)  carve((size_t)N * 4);
    int*   bsum   = (int*)  carve((size_t)nb * 4);
    int*   bbase  = (int*)  carve((size_t)nb * 4);
    int*   csrs   = (int*)  carve((size_t)E * 4);
    float* bufA   = (float*)carve((size_t)N * H * 4);
    float* bufB   = (float*)carve((size_t)N * H * 4);

    hipMemsetAsync(cnt, 0, (size_t)N * 4, stream);
    deg_kernel<<<(E + 255) / 256, 256, 0, stream>>>(ei, E, cnt);
    dis_kernel<<<(N + 255) / 256, 256, 0, stream>>>(cnt, dis, N);
    scan_block_sums<<<nb, 256, 0, stream>>>(cnt, N, bsum);
    scan_top<<<1, 1024, 0, stream>>>(bsum, nb, bbase, rowptr, N, E);
    scan_write<<<nb, 256, 0, stream>>>(cnt, N, bbase, rowptr, woff);
    fill_kernel<<<(E + 255) / 256, 256, 0, stream>>>(ei, E, woff, csrs);

    // layer 1
    mm1_kernel<<<((long long)N * H + 255) / 256, 256, 0, stream>>>(x, W1, dis, bufA, N);
    agg_kernel<<<(N + 7) / 8, 256, 0, stream>>>(rowptr, csrs, dis, bufA, bufB, N);

    // layer 2
    mm2_kernel<<<(N + 63) / 64, 256, 0, stream>>>(bufB, b1, W2, dis, bufA, N);
    agg_kernel<<<(N + 7) / 8, 256, 0, stream>>>(rowptr, csrs, dis, bufA, bufB, N);

    // pool
    pool_kernel<<<(G + 3) / 4, 128, 0, stream>>>(bufB, bat, b2, out, N, G);
}

// Round 4
// 392.393 us; speedup vs baseline: 14.8130x; 1.4844x over previous
//
#include <hip/hip_runtime.h>

#define H 128

__device__ __forceinline__ int lower_bound_i(const int* __restrict__ a, int n, int v) {
    int lo = 0, hi = n;
    while (lo < hi) { int m = (lo + hi) >> 1; if (a[m] < v) lo = m + 1; else hi = m; }
    return lo;
}

// ---- degree (int4-vectorized edge reads, atomic counts) ----
__global__ void deg_kernel(const int* __restrict__ ei, int E, int* __restrict__ cnt) {
    int i = blockIdx.x * blockDim.x + threadIdx.x;
    int e = i * 4;
    if (e >= E) return;
    if (e + 4 <= E) {
        int4 d = *(const int4*)(ei + E + e);
        atomicAdd(&cnt[d.x], 1); atomicAdd(&cnt[d.y], 1);
        atomicAdd(&cnt[d.z], 1); atomicAdd(&cnt[d.w], 1);
    } else {
        for (; e < E; ++e) atomicAdd(&cnt[ei[E + e]], 1);
    }
}

__global__ void dis_kernel(const int* __restrict__ cnt, float* __restrict__ dis, int N) {
    int i = blockIdx.x * blockDim.x + threadIdx.x;
    if (i < N) dis[i] = rsqrtf((float)cnt[i] + 1.0f);   // +1 self-loop
}

// ---- xp[n][0..7] = dis[n]*x[n][0..5], pad 0 ----
__global__ void padx_kernel(const float* __restrict__ x, const float* __restrict__ dis,
                            float* __restrict__ xp, int N) {
    int i = blockIdx.x * blockDim.x + threadIdx.x;
    int n = i >> 3, c = i & 7;
    if (n < N) xp[i] = (c < 6) ? x[n * 6 + c] * dis[n] : 0.f;
}

// ---- prefix scan (1024 elems / block) ----
__global__ __launch_bounds__(256) void scan_block_sums(const int* __restrict__ cnt, int N,
                                                       int* __restrict__ bsum) {
    __shared__ int s[256];
    int b = blockIdx.x, t = threadIdx.x;
    int idx0 = b * 1024 + t * 4;
    int v = 0;
    #pragma unroll
    for (int j = 0; j < 4; ++j) if (idx0 + j < N) v += cnt[idx0 + j];
    s[t] = v;
    __syncthreads();
    for (int off = 128; off > 0; off >>= 1) {
        if (t < off) s[t] += s[t + off];
        __syncthreads();
    }
    if (t == 0) bsum[b] = s[0];
}

__global__ __launch_bounds__(1024) void scan_top(const int* __restrict__ bsum, int nb,
                                                 int* __restrict__ bbase,
                                                 int* __restrict__ rowptr, int N, int E) {
    __shared__ int s[1024];
    int t = threadIdx.x;
    int own = (t < nb) ? bsum[t] : 0;
    s[t] = own;
    __syncthreads();
    for (int off = 1; off < 1024; off <<= 1) {
        int v = (t >= off) ? s[t - off] : 0;
        __syncthreads();
        s[t] += v;
        __syncthreads();
    }
    if (t < nb) bbase[t] = s[t] - own;
    if (t == 0) rowptr[N] = E;
}

__global__ __launch_bounds__(256) void scan_write(const int* __restrict__ cnt, int N,
                                                  const int* __restrict__ bbase,
                                                  int* __restrict__ rowptr,
                                                  int* __restrict__ woff) {
    __shared__ int s[256];
    int b = blockIdx.x, t = threadIdx.x;
    int idx0 = b * 1024 + t * 4;
    int v[4];
    int tot = 0;
    #pragma unroll
    for (int j = 0; j < 4; ++j) { v[j] = (idx0 + j < N) ? cnt[idx0 + j] : 0; tot += v[j]; }
    s[t] = tot;
    __syncthreads();
    for (int off = 1; off < 256; off <<= 1) {
        int u = (t >= off) ? s[t - off] : 0;
        __syncthreads();
        s[t] += u;
        __syncthreads();
    }
    int p = bbase[b] + s[t] - tot;
    #pragma unroll
    for (int j = 0; j < 4; ++j) {
        if (idx0 + j < N) { rowptr[idx0 + j] = p; woff[idx0 + j] = p; p += v[j]; }
    }
}

// ---- XCD-partitioned CSR fill: p = bid&7 handles dst in [p*N/8,(p+1)*N/8) ----
__global__ __launch_bounds__(256) void fill_part_kernel(const int* __restrict__ ei, int E, int N,
                                                        int* __restrict__ woff,
                                                        int* __restrict__ csr) {
    int p = blockIdx.x & 7;
    int ns = gridDim.x >> 3;
    int s = blockIdx.x >> 3;
    long long e0 = (long long)s * E / ns, e1 = (long long)(s + 1) * E / ns;
    int lo = (int)((long long)p * N / 8), hi = (int)((long long)(p + 1) * N / 8);
    for (long long e = e0 + threadIdx.x; e < e1; e += 256) {
        int d = ei[E + e];
        if (d >= lo && d < hi) {
            int src = ei[e];
            int pos = atomicAdd(&woff[d], 1);
            csr[pos] = src;
        }
    }
}

// ---- aggX[d] = dis[d]*(xp[d] + sum xp[s]) ; 8 lanes/node over padded 8-float rows ----
__global__ __launch_bounds__(256) void aggx_kernel(const int* __restrict__ rowptr,
                                                   const int* __restrict__ csr,
                                                   const float* __restrict__ dis,
                                                   const float* __restrict__ xp,
                                                   float* __restrict__ aggx, int N) {
    int node = blockIdx.x * 32 + (threadIdx.x >> 3);
    if (node >= N) return;
    int c = threadIdx.x & 7;
    int j0 = rowptr[node], j1 = rowptr[node + 1];
    float acc = xp[node * 8 + c];
    int j = j0;
    for (; j + 4 <= j1; j += 4) {
        int s0 = csr[j], s1 = csr[j + 1], s2 = csr[j + 2], s3 = csr[j + 3];
        acc += (xp[s0 * 8 + c] + xp[s1 * 8 + c]) + (xp[s2 * 8 + c] + xp[s3 * 8 + c]);
    }
    for (; j < j1; ++j) acc += xp[csr[j] * 8 + c];
    aggx[node * 8 + c] = acc * dis[node];
}

// ---- hs[n][f] = dis[n] * relu( aggX[n][0..5] @ W1 + b1 )[f] ----
__global__ void mm1relu_kernel(const float* __restrict__ aggx, const float* __restrict__ W1,
                               const float* __restrict__ b1, const float* __restrict__ dis,
                               float* __restrict__ hs, int N) {
    __shared__ float w[6 * H];
    for (int i = threadIdx.x; i < 6 * H; i += blockDim.x) w[i] = W1[i];
    __syncthreads();
    int idx = blockIdx.x * blockDim.x + threadIdx.x;
    int n = idx >> 7, f = idx & 127;
    if (n < N) {
        const float* ar = aggx + (long long)n * 8;
        float acc = b1[f];
        #pragma unroll
        for (int k = 0; k < 6; ++k) acc += ar[k] * w[k * H + f];
        hs[idx] = fmaxf(acc, 0.f) * dis[n];
    }
}

// ---- aggZ[d] = dis[d]*(hs[d] + sum hs[s]) ; 32 lanes/node, float4, unroll 8/4 ----
__global__ __launch_bounds__(256) void aggz_kernel(const int* __restrict__ rowptr,
                                                   const int* __restrict__ csr,
                                                   const float* __restrict__ dis,
                                                   const float* __restrict__ hs,
                                                   float* __restrict__ out, int N) {
    int node = blockIdx.x * 8 + (threadIdx.x >> 5);
    if (node >= N) return;
    int c = threadIdx.x & 31;
    const float4* hs4 = (const float4*)hs;
    int j0 = rowptr[node], j1 = rowptr[node + 1];
    float4 acc = hs4[(long long)node * 32 + c];
    int j = j0;
    for (; j + 8 <= j1; j += 8) {
        int s0 = csr[j], s1 = csr[j+1], s2 = csr[j+2], s3 = csr[j+3];
        int s4 = csr[j+4], s5 = csr[j+5], s6 = csr[j+6], s7 = csr[j+7];
        float4 v0 = hs4[(long long)s0 * 32 + c];
        float4 v1 = hs4[(long long)s1 * 32 + c];
        float4 v2 = hs4[(long long)s2 * 32 + c];
        float4 v3 = hs4[(long long)s3 * 32 + c];
        float4 v4 = hs4[(long long)s4 * 32 + c];
        float4 v5 = hs4[(long long)s5 * 32 + c];
        float4 v6 = hs4[(long long)s6 * 32 + c];
        float4 v7 = hs4[(long long)s7 * 32 + c];
        acc.x += ((v0.x + v1.x) + (v2.x + v3.x)) + ((v4.x + v5.x) + (v6.x + v7.x));
        acc.y += ((v0.y + v1.y) + (v2.y + v3.y)) + ((v4.y + v5.y) + (v6.y + v7.y));
        acc.z += ((v0.z + v1.z) + (v2.z + v3.z)) + ((v4.z + v5.z) + (v6.z + v7.z));
        acc.w += ((v0.w + v1.w) + (v2.w + v3.w)) + ((v4.w + v5.w) + (v6.w + v7.w));
    }
    for (; j + 4 <= j1; j += 4) {
        int s0 = csr[j], s1 = csr[j+1], s2 = csr[j+2], s3 = csr[j+3];
        float4 v0 = hs4[(long long)s0 * 32 + c];
        float4 v1 = hs4[(long long)s1 * 32 + c];
        float4 v2 = hs4[(long long)s2 * 32 + c];
        float4 v3 = hs4[(long long)s3 * 32 + c];
        acc.x += (v0.x + v1.x) + (v2.x + v3.x);
        acc.y += (v0.y + v1.y) + (v2.y + v3.y);
        acc.z += (v0.z + v1.z) + (v2.z + v3.z);
        acc.w += (v0.w + v1.w) + (v2.w + v3.w);
    }
    for (; j < j1; ++j) {
        float4 v = hs4[(long long)csr[j] * 32 + c];
        acc.x += v.x; acc.y += v.y; acc.z += v.z; acc.w += v.w;
    }
    float dd = dis[node];
    float4 o; o.x = acc.x * dd; o.y = acc.y * dd; o.z = acc.z * dd; o.w = acc.w * dd;
    ((float4*)out)[(long long)node * 32 + c] = o;
}

// ---- pmean[g] = mean(aggZ rows in segment), pcnt[g] = count ----
__global__ __launch_bounds__(128) void pool_kernel(const float* __restrict__ aggz,
                                                   const int* __restrict__ batch,
                                                   float* __restrict__ pmean,
                                                   int* __restrict__ pcnt, int N, int G) {
    int g = blockIdx.x * 4 + (threadIdx.x >> 5);
    int c = threadIdx.x & 31;
    if (g >= G) return;
    int start = lower_bound_i(batch, N, g);
    int end   = lower_bound_i(batch, N, g + 1);
    const float4* a4 = (const float4*)aggz;
    float4 acc = make_float4(0.f, 0.f, 0.f, 0.f);
    for (int n = start; n < end; ++n) {
        float4 v = a4[(long long)n * 32 + c];
        acc.x += v.x; acc.y += v.y; acc.z += v.z; acc.w += v.w;
    }
    int cnt = end - start;
    float inv = (cnt > 0) ? 1.f / (float)cnt : 0.f;
    float4 o = make_float4(acc.x * inv, acc.y * inv, acc.z * inv, acc.w * inv);
    ((float4*)pmean)[(long long)g * 32 + c] = o;
    if (c == 0) pcnt[g] = cnt;
}

// ---- out[g] = pcnt>0 ? pmean[g] @ W2 + b2 : 0 ----
__global__ __launch_bounds__(256) void out_kernel(const float* __restrict__ pmean,
                                                  const int* __restrict__ pcnt,
                                                  const float* __restrict__ W2,
                                                  const float* __restrict__ b2,
                                                  float* __restrict__ out, int G) {
    int g = blockIdx.x * 2 + (threadIdx.x >> 7);
    int f = threadIdx.x & 127;
    if (g >= G) return;
    if (pcnt[g] == 0) { out[(long long)g * H + f] = 0.f; return; }
    const float* pr = pmean + (long long)g * H;
    float acc = b2[f];
    #pragma unroll 8
    for (int k = 0; k < H; ++k) acc += pr[k] * W2[k * H + f];
    out[(long long)g * H + f] = acc;
}

extern "C" void kernel_launch(void* const* d_in, const int* in_sizes, int n_in,
                              void* d_out, int out_size, void* d_ws, size_t ws_size,
                              hipStream_t stream) {
    const float* x   = (const float*)d_in[0];
    const int*   ei  = (const int*)d_in[1];
    const int*   bat = (const int*)d_in[2];
    const float* W1  = (const float*)d_in[4];
    const float* b1  = (const float*)d_in[5];
    const float* W2  = (const float*)d_in[6];
    const float* b2  = (const float*)d_in[7];
    float* out = (float*)d_out;

    int N = in_sizes[0] / 6;
    int E = in_sizes[1] / 2;
    int G = out_size / H;
    int nb = (N + 1023) / 1024;

    char* ws = (char*)d_ws;
    size_t off = 0;
    auto carve = [&](size_t bytes) { void* p = ws + off; off = (off + bytes + 255) & ~(size_t)255; return p; };
    // persistent through aggz
    float* dis    = (float*)carve((size_t)N * 4);
    int*   rowptr = (int*)  carve((size_t)(N + 1) * 4);
    int*   csr    = (int*)  carve((size_t)E * 4);
    float* hs     = (float*)carve((size_t)N * H * 4);
    // region R: early-phase scratch, later overwritten by aggZ
    char*  R      = (char*) carve((size_t)N * H * 4);
    int*   cnt    = (int*)  (R);
    int*   woff   = (int*)  (R + (512 << 10));
    float* xp     = (float*)(R + (1 << 20));
    float* aggx   = (float*)(R + ((1 << 20) + 3355648));   // 1MB + 3.2MB(ceil,256-al)
    int*   bsum   = (int*)  (R + (8 << 20));
    int*   bbase  = (int*)  (R + (8 << 20) + 4096);
    float* aggz   = (float*)R;
    // small tail buffers
    float* pmean  = (float*)carve((size_t)G * H * 4);
    int*   pcnt   = (int*)  carve((size_t)G * 4);

    hipMemsetAsync(cnt, 0, (size_t)N * 4, stream);
    deg_kernel<<<((E + 3) / 4 + 255) / 256, 256, 0, stream>>>(ei, E, cnt);
    dis_kernel<<<(N + 255) / 256, 256, 0, stream>>>(cnt, dis, N);
    padx_kernel<<<((long long)N * 8 + 255) / 256, 256, 0, stream>>>(x, dis, xp, N);
    scan_block_sums<<<nb, 256, 0, stream>>>(cnt, N, bsum);
    scan_top<<<1, 1024, 0, stream>>>(bsum, nb, bbase, rowptr, N, E);
    scan_write<<<nb, 256, 0, stream>>>(cnt, N, bbase, rowptr, woff);
    fill_part_kernel<<<1024, 256, 0, stream>>>(ei, E, N, woff, csr);

    // layer 1: aggregate x (6 feats) then GEMM 6->128 (+bias, relu, pre-scale dis)
    aggx_kernel<<<(N + 31) / 32, 256, 0, stream>>>(rowptr, csr, dis, xp, aggx, N);
    mm1relu_kernel<<<((long long)N * H + 255) / 256, 256, 0, stream>>>(aggx, W1, b1, dis, hs, N);

    // layer 2 aggregation (128 feats) -> aggZ (overwrites R)
    aggz_kernel<<<(N + 7) / 8, 256, 0, stream>>>(rowptr, csr, dis, hs, aggz, N);

    // pool then tiny GEMM with W2 + b2 (empty graphs -> 0)
    pool_kernel<<<(G + 3) / 4, 128, 0, stream>>>(aggz, bat, pmean, pcnt, N, G);
    out_kernel<<<(G + 1) / 2, 256, 0, stream>>>(pmean, pcnt, W2, b2, out, G);
}

// Round 5
// 344.120 us; speedup vs baseline: 16.8909x; 1.1403x over previous
//
#include <hip/hip_runtime.h>

#define H 128

__device__ __forceinline__ int lower_bound_i(const int* __restrict__ a, int n, int v) {
    int lo = 0, hi = n;
    while (lo < hi) { int m = (lo + hi) >> 1; if (a[m] < v) lo = m + 1; else hi = m; }
    return lo;
}

// bf16 helpers (round-to-nearest-even pack, cheap unpack)
__device__ __forceinline__ unsigned bf16pack(float a, float b) {
    unsigned ua = __float_as_uint(a), ub = __float_as_uint(b);
    ua += 0x7fffu + ((ua >> 16) & 1u);
    ub += 0x7fffu + ((ub >> 16) & 1u);
    return (ua >> 16) | (ub & 0xffff0000u);
}
__device__ __forceinline__ float bflo(unsigned u) { return __uint_as_float(u << 16); }
__device__ __forceinline__ float bfhi(unsigned u) { return __uint_as_float(u & 0xffff0000u); }

// ---- degree ----
__global__ void deg_kernel(const int* __restrict__ ei, int E, int* __restrict__ cnt) {
    int i = blockIdx.x * blockDim.x + threadIdx.x;
    int e = i * 4;
    if (e >= E) return;
    if (e + 4 <= E) {
        int4 d = *(const int4*)(ei + E + e);
        atomicAdd(&cnt[d.x], 1); atomicAdd(&cnt[d.y], 1);
        atomicAdd(&cnt[d.z], 1); atomicAdd(&cnt[d.w], 1);
    } else {
        for (; e < E; ++e) atomicAdd(&cnt[ei[E + e]], 1);
    }
}

// ---- fused: dis[n] = rsqrt(deg+1);  xp[n] = bf16(x[n][0..5]*dis[n]) padded to 8 ----
__global__ void prep_kernel(const int* __restrict__ cnt, const float* __restrict__ x,
                            float* __restrict__ dis, uint4* __restrict__ xp, int N) {
    int n = blockIdx.x * blockDim.x + threadIdx.x;
    if (n >= N) return;
    float dd = rsqrtf((float)cnt[n] + 1.0f);
    dis[n] = dd;
    const float* xr = x + (size_t)n * 6;
    uint4 o;
    o.x = bf16pack(xr[0] * dd, xr[1] * dd);
    o.y = bf16pack(xr[2] * dd, xr[3] * dd);
    o.z = bf16pack(xr[4] * dd, xr[5] * dd);
    o.w = 0u;
    xp[n] = o;
}

// ---- prefix scan (1024 elems / block) ----
__global__ __launch_bounds__(256) void scan_block_sums(const int* __restrict__ cnt, int N,
                                                       int* __restrict__ bsum) {
    __shared__ int s[256];
    int b = blockIdx.x, t = threadIdx.x;
    int idx0 = b * 1024 + t * 4;
    int v = 0;
    #pragma unroll
    for (int j = 0; j < 4; ++j) if (idx0 + j < N) v += cnt[idx0 + j];
    s[t] = v;
    __syncthreads();
    for (int off = 128; off > 0; off >>= 1) {
        if (t < off) s[t] += s[t + off];
        __syncthreads();
    }
    if (t == 0) bsum[b] = s[0];
}

__global__ __launch_bounds__(1024) void scan_top(const int* __restrict__ bsum, int nb,
                                                 int* __restrict__ bbase,
                                                 int* __restrict__ rowptr, int N, int E) {
    __shared__ int s[1024];
    int t = threadIdx.x;
    int own = (t < nb) ? bsum[t] : 0;
    s[t] = own;
    __syncthreads();
    for (int off = 1; off < 1024; off <<= 1) {
        int v = (t >= off) ? s[t - off] : 0;
        __syncthreads();
        s[t] += v;
        __syncthreads();
    }
    if (t < nb) bbase[t] = s[t] - own;
    if (t == 0) rowptr[N] = E;
}

__global__ __launch_bounds__(256) void scan_write(const int* __restrict__ cnt, int N,
                                                  const int* __restrict__ bbase,
                                                  int* __restrict__ rowptr,
                                                  int* __restrict__ woff) {
    __shared__ int s[256];
    int b = blockIdx.x, t = threadIdx.x;
    int idx0 = b * 1024 + t * 4;
    int v[4];
    int tot = 0;
    #pragma unroll
    for (int j = 0; j < 4; ++j) { v[j] = (idx0 + j < N) ? cnt[idx0 + j] : 0; tot += v[j]; }
    s[t] = tot;
    __syncthreads();
    for (int off = 1; off < 256; off <<= 1) {
        int u = (t >= off) ? s[t - off] : 0;
        __syncthreads();
        s[t] += u;
        __syncthreads();
    }
    int p = bbase[b] + s[t] - tot;
    #pragma unroll
    for (int j = 0; j < 4; ++j) {
        if (idx0 + j < N) { rowptr[idx0 + j] = p; woff[idx0 + j] = p; p += v[j]; }
    }
}

// ---- partitioned CSR fill: p = bid&3 handles dst in [p*N/4,(p+1)*N/4) ----
__global__ __launch_bounds__(256) void fill_part_kernel(const int* __restrict__ ei, int E, int N,
                                                        int* __restrict__ woff,
                                                        int* __restrict__ csr) {
    int p = blockIdx.x & 3;
    int ns = gridDim.x >> 2;
    int s = blockIdx.x >> 2;
    long long e0 = (long long)s * E / ns, e1 = (long long)(s + 1) * E / ns;
    int lo = (int)((long long)p * N / 4), hi = (int)((long long)(p + 1) * N / 4);
    for (long long e = e0 + threadIdx.x; e < e1; e += 256) {
        int d = ei[E + e];
        if (d >= lo && d < hi) {
            int src = ei[e];
            int pos = atomicAdd(&woff[d], 1);
            csr[pos] = src;
        }
    }
}

// ---- aggX: lane-per-node gather of 16B bf16 rows ----
__global__ __launch_bounds__(256) void aggx_kernel(const int* __restrict__ rowptr,
                                                   const int* __restrict__ csr,
                                                   const float* __restrict__ dis,
                                                   const uint4* __restrict__ xp,
                                                   float* __restrict__ aggx, int N) {
    int n = blockIdx.x * 256 + threadIdx.x;
    if (n >= N) return;
    int j0 = rowptr[n], j1 = rowptr[n + 1];
    uint4 sv = xp[n];
    float a0 = bflo(sv.x), a1 = bfhi(sv.x), a2 = bflo(sv.y),
          a3 = bfhi(sv.y), a4 = bflo(sv.z), a5 = bfhi(sv.z);
    int j = j0;
    for (; j + 2 <= j1; j += 2) {
        uint4 v0 = xp[csr[j]], v1 = xp[csr[j + 1]];
        a0 += bflo(v0.x) + bflo(v1.x); a1 += bfhi(v0.x) + bfhi(v1.x);
        a2 += bflo(v0.y) + bflo(v1.y); a3 += bfhi(v0.y) + bfhi(v1.y);
        a4 += bflo(v0.z) + bflo(v1.z); a5 += bfhi(v0.z) + bfhi(v1.z);
    }
    if (j < j1) {
        uint4 v = xp[csr[j]];
        a0 += bflo(v.x); a1 += bfhi(v.x); a2 += bflo(v.y);
        a3 += bfhi(v.y); a4 += bflo(v.z); a5 += bfhi(v.z);
    }
    float dd = dis[n];
    float4* out4 = (float4*)(aggx + (size_t)n * 8);
    out4[0] = make_float4(a0 * dd, a1 * dd, a2 * dd, a3 * dd);
    out4[1] = make_float4(a4 * dd, a5 * dd, 0.f, 0.f);
}

// ---- hs[n][f] = bf16( dis[n] * relu(aggX[n][0..5] @ W1 + b1) ), 2 feats/thread ----
__global__ void mm1relu_kernel(const float* __restrict__ aggx, const float* __restrict__ W1,
                               const float* __restrict__ b1, const float* __restrict__ dis,
                               unsigned* __restrict__ hs, int N) {
    __shared__ float w[6 * H];
    __shared__ float bsh[H];
    for (int i = threadIdx.x; i < 6 * H; i += blockDim.x) w[i] = W1[i];
    for (int i = threadIdx.x; i < H; i += blockDim.x) bsh[i] = b1[i];
    __syncthreads();
    int idx = blockIdx.x * blockDim.x + threadIdx.x;
    int n = idx >> 6, f2 = idx & 63;
    if (n >= N) return;
    const float* ar = aggx + (size_t)n * 8;
    float a0 = ar[0], a1 = ar[1], a2 = ar[2], a3 = ar[3], a4 = ar[4], a5 = ar[5];
    float acc0 = bsh[2 * f2], acc1 = bsh[2 * f2 + 1];
    acc0 += a0 * w[0 * H + 2 * f2] + a1 * w[1 * H + 2 * f2] + a2 * w[2 * H + 2 * f2]
          + a3 * w[3 * H + 2 * f2] + a4 * w[4 * H + 2 * f2] + a5 * w[5 * H + 2 * f2];
    acc1 += a0 * w[0 * H + 2 * f2 + 1] + a1 * w[1 * H + 2 * f2 + 1] + a2 * w[2 * H + 2 * f2 + 1]
          + a3 * w[3 * H + 2 * f2 + 1] + a4 * w[4 * H + 2 * f2 + 1] + a5 * w[5 * H + 2 * f2 + 1];
    float dd = dis[n];
    hs[idx] = bf16pack(fmaxf(acc0, 0.f) * dd, fmaxf(acc1, 0.f) * dd);
}

#define ACC8(v) do { \
    acc0 += bflo((v).x); acc1 += bfhi((v).x); \
    acc2 += bflo((v).y); acc3 += bfhi((v).y); \
    acc4 += bflo((v).z); acc5 += bfhi((v).z); \
    acc6 += bflo((v).w); acc7 += bfhi((v).w); } while (0)

// ---- aggZ[d] = bf16( dis[d]*(hs[d] + sum hs[s]) ) ; 16 lanes/node, 16B bf16 chunks ----
__global__ __launch_bounds__(256, 8) void aggz_kernel(const int* __restrict__ rowptr,
                                                      const int* __restrict__ csr,
                                                      const float* __restrict__ dis,
                                                      const uint4* __restrict__ hs,
                                                      uint4* __restrict__ out, int N) {
    int node = blockIdx.x * 16 + (threadIdx.x >> 4);
    if (node >= N) return;
    int c = threadIdx.x & 15;
    int j0 = rowptr[node], j1 = rowptr[node + 1];
    uint4 sv = hs[(size_t)node * 16 + c];
    float acc0 = bflo(sv.x), acc1 = bfhi(sv.x), acc2 = bflo(sv.y), acc3 = bfhi(sv.y),
          acc4 = bflo(sv.z), acc5 = bfhi(sv.z), acc6 = bflo(sv.w), acc7 = bfhi(sv.w);
    int j = j0;
    for (; j + 8 <= j1; j += 8) {
        int s0 = csr[j], s1 = csr[j+1], s2 = csr[j+2], s3 = csr[j+3];
        int s4 = csr[j+4], s5 = csr[j+5], s6 = csr[j+6], s7 = csr[j+7];
        uint4 v0 = hs[(size_t)s0 * 16 + c];
        uint4 v1 = hs[(size_t)s1 * 16 + c];
        uint4 v2 = hs[(size_t)s2 * 16 + c];
        uint4 v3 = hs[(size_t)s3 * 16 + c];
        uint4 v4 = hs[(size_t)s4 * 16 + c];
        uint4 v5 = hs[(size_t)s5 * 16 + c];
        uint4 v6 = hs[(size_t)s6 * 16 + c];
        uint4 v7 = hs[(size_t)s7 * 16 + c];
        ACC8(v0); ACC8(v1); ACC8(v2); ACC8(v3);
        ACC8(v4); ACC8(v5); ACC8(v6); ACC8(v7);
    }
    for (; j < j1; ++j) {
        uint4 v = hs[(size_t)csr[j] * 16 + c];
        ACC8(v);
    }
    float dd = dis[node];
    uint4 o;
    o.x = bf16pack(acc0 * dd, acc1 * dd);
    o.y = bf16pack(acc2 * dd, acc3 * dd);
    o.z = bf16pack(acc4 * dd, acc5 * dd);
    o.w = bf16pack(acc6 * dd, acc7 * dd);
    out[(size_t)node * 16 + c] = o;
}

// ---- pmean[g] = mean(aggZ bf16 rows), pcnt[g] ; 32 lanes/graph ----
__global__ __launch_bounds__(256) void pool_kernel(const uint2* __restrict__ aggz,
                                                   const int* __restrict__ batch,
                                                   float* __restrict__ pmean,
                                                   int* __restrict__ pcnt, int N, int G) {
    int g = blockIdx.x * 8 + (threadIdx.x >> 5);
    if (g >= G) return;
    int c = threadIdx.x & 31;
    int start = lower_bound_i(batch, N, g);
    int end   = lower_bound_i(batch, N, g + 1);
    float4 acc = make_float4(0.f, 0.f, 0.f, 0.f);
    for (int n = start; n < end; ++n) {
        uint2 v = aggz[(size_t)n * 32 + c];
        acc.x += bflo(v.x); acc.y += bfhi(v.x);
        acc.z += bflo(v.y); acc.w += bfhi(v.y);
    }
    int cnt = end - start;
    float inv = (cnt > 0) ? 1.f / (float)cnt : 0.f;
    ((float4*)pmean)[(size_t)g * 32 + c] =
        make_float4(acc.x * inv, acc.y * inv, acc.z * inv, acc.w * inv);
    if (c == 0) pcnt[g] = cnt;
}

// ---- out[g] = pcnt>0 ? pmean[g] @ W2 + b2 : 0 ; W2 in 64KB LDS, 8 graphs/block ----
__global__ __launch_bounds__(128) void out_kernel(const float* __restrict__ pmean,
                                                  const int* __restrict__ pcnt,
                                                  const float* __restrict__ W2,
                                                  const float* __restrict__ b2,
                                                  float* __restrict__ out, int G) {
    __shared__ float w[H * H];   // exactly 64 KB
    {
        const float4* W4 = (const float4*)W2;
        float4* wl = (float4*)w;
        for (int i = threadIdx.x; i < H * H / 4; i += 128) wl[i] = W4[i];
    }
    __syncthreads();
    int f = threadIdx.x;
    float bb = b2[f];
    for (int gi = 0; gi < 8; ++gi) {
        int g = blockIdx.x * 8 + gi;
        if (g >= G) break;
        if (pcnt[g] == 0) { out[(size_t)g * H + f] = 0.f; continue; }
        const float* pr = pmean + (size_t)g * H;
        float o = bb;
        #pragma unroll 8
        for (int k = 0; k < H; ++k) o += pr[k] * w[k * H + f];
        out[(size_t)g * H + f] = o;
    }
}

extern "C" void kernel_launch(void* const* d_in, const int* in_sizes, int n_in,
                              void* d_out, int out_size, void* d_ws, size_t ws_size,
                              hipStream_t stream) {
    const float* x   = (const float*)d_in[0];
    const int*   ei  = (const int*)d_in[1];
    const int*   bat = (const int*)d_in[2];
    const float* W1  = (const float*)d_in[4];
    const float* b1  = (const float*)d_in[5];
    const float* W2  = (const float*)d_in[6];
    const float* b2  = (const float*)d_in[7];
    float* out = (float*)d_out;

    int N = in_sizes[0] / 6;
    int E = in_sizes[1] / 2;
    int G = out_size / H;
    int nb = (N + 1023) / 1024;

    char* ws = (char*)d_ws;
    size_t off = 0;
    auto carve = [&](size_t bytes) { void* p = ws + off; off = (off + bytes + 255) & ~(size_t)255; return p; };
    // persistent
    float*    dis    = (float*)carve((size_t)N * 4);
    int*      rowptr = (int*)  carve((size_t)(N + 1) * 4);
    int*      csr    = (int*)  carve((size_t)E * 4);
    unsigned* hs     = (unsigned*)carve((size_t)N * H * 2);   // bf16 packed
    // region R: early scratch, later aggz (bf16, N*H*2)
    char*  R      = (char*) carve((size_t)N * H * 2);
    int*   cnt    = (int*)  (R);
    int*   woff   = (int*)  (R + (512 << 10));
    uint4* xp     = (uint4*)(R + (1 << 20));                  // N*16 B
    float* aggx   = (float*)(R + (3 << 20));                  // N*32 B
    int*   bsum   = (int*)  (R + (8 << 20));
    int*   bbase  = (int*)  (R + (8 << 20) + 65536);
    uint4* aggz   = (uint4*)R;
    // small tail
    float* pmean  = (float*)carve((size_t)G * H * 4);
    int*   pcnt   = (int*)  carve((size_t)G * 4);

    hipMemsetAsync(cnt, 0, (size_t)N * 4, stream);
    deg_kernel<<<((E + 3) / 4 + 255) / 256, 256, 0, stream>>>(ei, E, cnt);
    prep_kernel<<<(N + 255) / 256, 256, 0, stream>>>(cnt, x, dis, xp, N);
    scan_block_sums<<<nb, 256, 0, stream>>>(cnt, N, bsum);
    scan_top<<<1, 1024, 0, stream>>>(bsum, nb, bbase, rowptr, N, E);
    scan_write<<<nb, 256, 0, stream>>>(cnt, N, bbase, rowptr, woff);
    fill_part_kernel<<<1024, 256, 0, stream>>>(ei, E, N, woff, csr);

    // layer 1
    aggx_kernel<<<(N + 255) / 256, 256, 0, stream>>>(rowptr, csr, dis, xp, aggx, N);
    mm1relu_kernel<<<((size_t)N * 64 + 255) / 256, 256, 0, stream>>>(aggx, W1, b1, dis, hs, N);

    // layer 2 aggregation (bf16 gather) -> aggz (overwrites R)
    aggz_kernel<<<(N + 15) / 16, 256, 0, stream>>>(rowptr, csr, dis, (const uint4*)hs, aggz, N);

    // pool + final GEMM
    pool_kernel<<<(G + 7) / 8, 256, 0, stream>>>((const uint2*)aggz, bat, pmean, pcnt, N, G);
    out_kernel<<<(G + 7) / 8, 128, 0, stream>>>(pmean, pcnt, W2, b2, out, G);
}

// Round 6
// 250.272 us; speedup vs baseline: 23.2248x; 1.3750x over previous
//
#include <hip/hip_runtime.h>

#define H 128
#define RBITS 9
#define RR 512               // nodes per bucket (1<<RBITS)
#define PACK_SHIFT 23        // pack = src | (dlow << 23); src < 2^23, dlow < 2^9
#define TS 8192              // edges staged per block in bucketB
#define SRCCAP 12800         // group-kernel LDS src buffer (bucket avg ~8200)

__device__ __forceinline__ int lower_bound_i(const int* __restrict__ a, int n, int v) {
    int lo = 0, hi = n;
    while (lo < hi) { int m = (lo + hi) >> 1; if (a[m] < v) lo = m + 1; else hi = m; }
    return lo;
}

// bf16 helpers (round-to-nearest-even pack, cheap unpack)
__device__ __forceinline__ unsigned bf16pack(float a, float b) {
    unsigned ua = __float_as_uint(a), ub = __float_as_uint(b);
    ua += 0x7fffu + ((ua >> 16) & 1u);
    ub += 0x7fffu + ((ub >> 16) & 1u);
    return (ua >> 16) | (ub & 0xffff0000u);
}
__device__ __forceinline__ float bflo(unsigned u) { return __uint_as_float(u << 16); }
__device__ __forceinline__ float bfhi(unsigned u) { return __uint_as_float(u & 0xffff0000u); }

// ---- pass 1: per-bucket edge counts (dst>>RBITS) ----
__global__ __launch_bounds__(256) void bucketA_kernel(const int* __restrict__ ei, int E,
                                                      int NB, int* __restrict__ bcnt) {
    __shared__ int h[256];
    int t = threadIdx.x;
    h[t] = 0;
    __syncthreads();
    int e0 = blockIdx.x * 4096;
    int e1 = e0 + 4096 < E ? e0 + 4096 : E;
    for (int e = e0 + t; e < e1; e += 256)
        atomicAdd(&h[((unsigned)ei[E + e]) >> RBITS], 1);
    __syncthreads();
    if (t < NB && h[t] > 0) atomicAdd(&bcnt[t], h[t]);
}

// ---- pass 2: exclusive scan of bucket counts -> bbase, cursor ----
__global__ __launch_bounds__(256) void scan_buckets(const int* __restrict__ bcnt, int NB, int E,
                                                    int* __restrict__ bbase,
                                                    int* __restrict__ cursor) {
    __shared__ int A[256], B[256];
    int t = threadIdx.x;
    int v = (t < NB) ? bcnt[t] : 0;
    A[t] = v;
    __syncthreads();
    int* cur = A; int* nxt = B;
    for (int off = 1; off < 256; off <<= 1) {
        int val = cur[t];
        if (t >= off) val += cur[t - off];
        nxt[t] = val;
        __syncthreads();
        int* tmp = cur; cur = nxt; nxt = tmp;
    }
    int excl = cur[t] - v;
    if (t < NB) { bbase[t] = excl; cursor[t] = excl; }
    if (t == 0) bbase[NB] = E;
}

// ---- pass 3: LDS-staged bucket scatter; writes packed (src|dlow) coalesced ----
__global__ __launch_bounds__(256) void bucketB_kernel(const int* __restrict__ ei, int E,
                                                      int* __restrict__ cursor,
                                                      unsigned* __restrict__ pairs) {
    __shared__ int hist[256], hexcl[256], loff[256], gch[256];
    __shared__ int sA[256], sB[256];
    __shared__ unsigned staged[TS];
    __shared__ unsigned char sbk[TS];
    int t = threadIdx.x;
    int e0 = blockIdx.x * TS;
    int e1 = e0 + TS < E ? e0 + TS : E;
    int m = e1 - e0;
    hist[t] = 0;
    __syncthreads();
    for (int e = e0 + t; e < e1; e += 256)
        atomicAdd(&hist[((unsigned)ei[E + e]) >> RBITS], 1);
    __syncthreads();
    {   // exclusive scan of hist
        int v = hist[t];
        sA[t] = v;
        __syncthreads();
        int* cur = sA; int* nxt = sB;
        for (int off = 1; off < 256; off <<= 1) {
            int val = cur[t];
            if (t >= off) val += cur[t - off];
            nxt[t] = val;
            __syncthreads();
            int* tmp = cur; cur = nxt; nxt = tmp;
        }
        int excl = cur[t] - v;
        hexcl[t] = excl;
        loff[t] = excl;
        gch[t] = (v > 0) ? atomicAdd(&cursor[t], v) : 0;
    }
    __syncthreads();
    // place into LDS grouped by bucket
    for (int e = e0 + t; e < e1; e += 256) {
        unsigned d = (unsigned)ei[E + e];
        unsigned s = (unsigned)ei[e];
        int b = d >> RBITS;
        int pos = atomicAdd(&loff[b], 1);
        staged[pos] = s | ((d & (RR - 1)) << PACK_SHIFT);
        sbk[pos] = (unsigned char)b;
    }
    __syncthreads();
    // coalesced chunk write-out
    for (int i = t; i < m; i += 256) {
        int b = sbk[i];
        pairs[gch[b] + (i - hexcl[b])] = staged[i];
    }
}

// ---- pass 4: per-bucket grouping by dst; emits dis, rowptr, csr (all coalesced) ----
__global__ __launch_bounds__(256) void group_kernel(const unsigned* __restrict__ pairs,
                                                    const int* __restrict__ bbase,
                                                    int N, int NB, int E,
                                                    float* __restrict__ dis,
                                                    int* __restrict__ rowptr,
                                                    int* __restrict__ csr) {
    __shared__ int cntl[RR], woffl[RR];
    __shared__ int sA[RR], sB[RR];
    __shared__ unsigned srcbuf[SRCCAP];
    int b = blockIdx.x, t = threadIdx.x;
    int lo = b * RR;
    int nn = (N - lo < RR) ? (N - lo) : RR;
    int start = bbase[b], cnt = bbase[b + 1] - start;
    cntl[t] = 0; cntl[t + 256] = 0;
    __syncthreads();
    for (int i = t; i < cnt; i += 256)
        atomicAdd(&cntl[pairs[start + i] >> PACK_SHIFT], 1);
    __syncthreads();
    // inclusive scan over 512 (2 positions per thread, double-buffered)
    sA[t] = cntl[t]; sA[t + 256] = cntl[t + 256];
    __syncthreads();
    int* cur = sA; int* nxt = sB;
    for (int off = 1; off < 512; off <<= 1) {
        int v0 = cur[t];        if (t >= off)        v0 += cur[t - off];
        int v1 = cur[t + 256];  if (t + 256 >= off)  v1 += cur[t + 256 - off];
        nxt[t] = v0; nxt[t + 256] = v1;
        __syncthreads();
        int* tmp = cur; cur = nxt; nxt = tmp;
    }
    #pragma unroll
    for (int q = 0; q < 2; ++q) {
        int p = t + q * 256;
        if (p < nn) {
            int c = cntl[p];
            dis[lo + p] = rsqrtf((float)c + 1.0f);
            int excl = cur[p] - c;
            rowptr[lo + p] = start + excl;
            woffl[p] = excl;
        }
    }
    if (b == NB - 1 && t == 0) rowptr[N] = E;
    __syncthreads();
    bool fits = (cnt <= SRCCAP);
    for (int i = t; i < cnt; i += 256) {
        unsigned p = pairs[start + i];
        int dlow = p >> PACK_SHIFT;
        unsigned s = p & ((1u << PACK_SHIFT) - 1);
        int pos = atomicAdd(&woffl[dlow], 1);
        if (fits) srcbuf[pos] = s;
        else csr[start + pos] = (int)s;      // safety fallback, never taken here
    }
    __syncthreads();
    if (fits)
        for (int i = t; i < cnt; i += 256) csr[start + i] = (int)srcbuf[i];
}

// ---- xp[n] = bf16(x[n][0..5]*dis[n]) padded to 8 ----
__global__ void prep_kernel(const float* __restrict__ dis, const float* __restrict__ x,
                            uint4* __restrict__ xp, int N) {
    int n = blockIdx.x * blockDim.x + threadIdx.x;
    if (n >= N) return;
    float dd = dis[n];
    const float* xr = x + (size_t)n * 6;
    uint4 o;
    o.x = bf16pack(xr[0] * dd, xr[1] * dd);
    o.y = bf16pack(xr[2] * dd, xr[3] * dd);
    o.z = bf16pack(xr[4] * dd, xr[5] * dd);
    o.w = 0u;
    xp[n] = o;
}

// ---- aggX: lane-per-node gather of 16B bf16 rows ----
__global__ __launch_bounds__(256) void aggx_kernel(const int* __restrict__ rowptr,
                                                   const int* __restrict__ csr,
                                                   const float* __restrict__ dis,
                                                   const uint4* __restrict__ xp,
                                                   float* __restrict__ aggx, int N) {
    int n = blockIdx.x * 256 + threadIdx.x;
    if (n >= N) return;
    int j0 = rowptr[n], j1 = rowptr[n + 1];
    uint4 sv = xp[n];
    float a0 = bflo(sv.x), a1 = bfhi(sv.x), a2 = bflo(sv.y),
          a3 = bfhi(sv.y), a4 = bflo(sv.z), a5 = bfhi(sv.z);
    int j = j0;
    for (; j + 2 <= j1; j += 2) {
        uint4 v0 = xp[csr[j]], v1 = xp[csr[j + 1]];
        a0 += bflo(v0.x) + bflo(v1.x); a1 += bfhi(v0.x) + bfhi(v1.x);
        a2 += bflo(v0.y) + bflo(v1.y); a3 += bfhi(v0.y) + bfhi(v1.y);
        a4 += bflo(v0.z) + bflo(v1.z); a5 += bfhi(v0.z) + bfhi(v1.z);
    }
    if (j < j1) {
        uint4 v = xp[csr[j]];
        a0 += bflo(v.x); a1 += bfhi(v.x); a2 += bflo(v.y);
        a3 += bfhi(v.y); a4 += bflo(v.z); a5 += bfhi(v.z);
    }
    float dd = dis[n];
    float4* out4 = (float4*)(aggx + (size_t)n * 8);
    out4[0] = make_float4(a0 * dd, a1 * dd, a2 * dd, a3 * dd);
    out4[1] = make_float4(a4 * dd, a5 * dd, 0.f, 0.f);
}

// ---- hs[n][f] = bf16( dis[n] * relu(aggX[n][0..5] @ W1 + b1) ), 2 feats/thread ----
__global__ void mm1relu_kernel(const float* __restrict__ aggx, const float* __restrict__ W1,
                               const float* __restrict__ b1, const float* __restrict__ dis,
                               unsigned* __restrict__ hs, int N) {
    __shared__ float w[6 * H];
    __shared__ float bsh[H];
    for (int i = threadIdx.x; i < 6 * H; i += blockDim.x) w[i] = W1[i];
    for (int i = threadIdx.x; i < H; i += blockDim.x) bsh[i] = b1[i];
    __syncthreads();
    int idx = blockIdx.x * blockDim.x + threadIdx.x;
    int n = idx >> 6, f2 = idx & 63;
    if (n >= N) return;
    const float* ar = aggx + (size_t)n * 8;
    float a0 = ar[0], a1 = ar[1], a2 = ar[2], a3 = ar[3], a4 = ar[4], a5 = ar[5];
    float acc0 = bsh[2 * f2], acc1 = bsh[2 * f2 + 1];
    acc0 += a0 * w[0 * H + 2 * f2] + a1 * w[1 * H + 2 * f2] + a2 * w[2 * H + 2 * f2]
          + a3 * w[3 * H + 2 * f2] + a4 * w[4 * H + 2 * f2] + a5 * w[5 * H + 2 * f2];
    acc1 += a0 * w[0 * H + 2 * f2 + 1] + a1 * w[1 * H + 2 * f2 + 1] + a2 * w[2 * H + 2 * f2 + 1]
          + a3 * w[3 * H + 2 * f2 + 1] + a4 * w[4 * H + 2 * f2 + 1] + a5 * w[5 * H + 2 * f2 + 1];
    float dd = dis[n];
    hs[idx] = bf16pack(fmaxf(acc0, 0.f) * dd, fmaxf(acc1, 0.f) * dd);
}

#define ACC8(v) do { \
    acc0 += bflo((v).x); acc1 += bfhi((v).x); \
    acc2 += bflo((v).y); acc3 += bfhi((v).y); \
    acc4 += bflo((v).z); acc5 += bfhi((v).z); \
    acc6 += bflo((v).w); acc7 += bfhi((v).w); } while (0)

// ---- aggZ[d] = bf16( dis[d]*(hs[d] + sum hs[s]) ) ; 16 lanes/node, 16B bf16 chunks ----
__global__ __launch_bounds__(256, 8) void aggz_kernel(const int* __restrict__ rowptr,
                                                      const int* __restrict__ csr,
                                                      const float* __restrict__ dis,
                                                      const uint4* __restrict__ hs,
                                                      uint4* __restrict__ out, int N) {
    int node = blockIdx.x * 16 + (threadIdx.x >> 4);
    if (node >= N) return;
    int c = threadIdx.x & 15;
    int j0 = rowptr[node], j1 = rowptr[node + 1];
    uint4 sv = hs[(size_t)node * 16 + c];
    float acc0 = bflo(sv.x), acc1 = bfhi(sv.x), acc2 = bflo(sv.y), acc3 = bfhi(sv.y),
          acc4 = bflo(sv.z), acc5 = bfhi(sv.z), acc6 = bflo(sv.w), acc7 = bfhi(sv.w);
    int j = j0;
    for (; j + 8 <= j1; j += 8) {
        int s0 = csr[j], s1 = csr[j+1], s2 = csr[j+2], s3 = csr[j+3];
        int s4 = csr[j+4], s5 = csr[j+5], s6 = csr[j+6], s7 = csr[j+7];
        uint4 v0 = hs[(size_t)s0 * 16 + c];
        uint4 v1 = hs[(size_t)s1 * 16 + c];
        uint4 v2 = hs[(size_t)s2 * 16 + c];
        uint4 v3 = hs[(size_t)s3 * 16 + c];
        uint4 v4 = hs[(size_t)s4 * 16 + c];
        uint4 v5 = hs[(size_t)s5 * 16 + c];
        uint4 v6 = hs[(size_t)s6 * 16 + c];
        uint4 v7 = hs[(size_t)s7 * 16 + c];
        ACC8(v0); ACC8(v1); ACC8(v2); ACC8(v3);
        ACC8(v4); ACC8(v5); ACC8(v6); ACC8(v7);
    }
    for (; j < j1; ++j) {
        uint4 v = hs[(size_t)csr[j] * 16 + c];
        ACC8(v);
    }
    float dd = dis[node];
    uint4 o;
    o.x = bf16pack(acc0 * dd, acc1 * dd);
    o.y = bf16pack(acc2 * dd, acc3 * dd);
    o.z = bf16pack(acc4 * dd, acc5 * dd);
    o.w = bf16pack(acc6 * dd, acc7 * dd);
    out[(size_t)node * 16 + c] = o;
}

// ---- pmean[g] = mean(aggZ bf16 rows), pcnt[g] ; 32 lanes/graph ----
__global__ __launch_bounds__(256) void pool_kernel(const uint2* __restrict__ aggz,
                                                   const int* __restrict__ batch,
                                                   float* __restrict__ pmean,
                                                   int* __restrict__ pcnt, int N, int G) {
    int g = blockIdx.x * 8 + (threadIdx.x >> 5);
    if (g >= G) return;
    int c = threadIdx.x & 31;
    int start = lower_bound_i(batch, N, g);
    int end   = lower_bound_i(batch, N, g + 1);
    float4 acc = make_float4(0.f, 0.f, 0.f, 0.f);
    for (int n = start; n < end; ++n) {
        uint2 v = aggz[(size_t)n * 32 + c];
        acc.x += bflo(v.x); acc.y += bfhi(v.x);
        acc.z += bflo(v.y); acc.w += bfhi(v.y);
    }
    int cnt = end - start;
    float inv = (cnt > 0) ? 1.f / (float)cnt : 0.f;
    ((float4*)pmean)[(size_t)g * 32 + c] =
        make_float4(acc.x * inv, acc.y * inv, acc.z * inv, acc.w * inv);
    if (c == 0) pcnt[g] = cnt;
}

// ---- out[g] = pcnt>0 ? pmean[g] @ W2 + b2 : 0 ; W2 in 64KB LDS, 8 graphs/block ----
__global__ __launch_bounds__(128) void out_kernel(const float* __restrict__ pmean,
                                                  const int* __restrict__ pcnt,
                                                  const float* __restrict__ W2,
                                                  const float* __restrict__ b2,
                                                  float* __restrict__ out, int G) {
    __shared__ float w[H * H];
    {
        const float4* W4 = (const float4*)W2;
        float4* wl = (float4*)w;
        for (int i = threadIdx.x; i < H * H / 4; i += 128) wl[i] = W4[i];
    }
    __syncthreads();
    int f = threadIdx.x;
    float bb = b2[f];
    for (int gi = 0; gi < 8; ++gi) {
        int g = blockIdx.x * 8 + gi;
        if (g >= G) break;
        if (pcnt[g] == 0) { out[(size_t)g * H + f] = 0.f; continue; }
        const float* pr = pmean + (size_t)g * H;
        float o = bb;
        #pragma unroll 8
        for (int k = 0; k < H; ++k) o += pr[k] * w[k * H + f];
        out[(size_t)g * H + f] = o;
    }
}

extern "C" void kernel_launch(void* const* d_in, const int* in_sizes, int n_in,
                              void* d_out, int out_size, void* d_ws, size_t ws_size,
                              hipStream_t stream) {
    const float* x   = (const float*)d_in[0];
    const int*   ei  = (const int*)d_in[1];
    const int*   bat = (const int*)d_in[2];
    const float* W1  = (const float*)d_in[4];
    const float* b1  = (const float*)d_in[5];
    const float* W2  = (const float*)d_in[6];
    const float* b2  = (const float*)d_in[7];
    float* out = (float*)d_out;

    int N = in_sizes[0] / 6;
    int E = in_sizes[1] / 2;
    int G = out_size / H;
    int NB = (N + RR - 1) / RR;          // buckets (<=256)

    char* ws = (char*)d_ws;
    size_t off = 0;
    auto carve = [&](size_t bytes) { void* p = ws + off; off = (off + bytes + 255) & ~(size_t)255; return p; };
    // persistent
    float*    dis    = (float*)carve((size_t)N * 4);
    int*      rowptr = (int*)  carve((size_t)(N + 1) * 4);
    int*      csr    = (int*)  carve((size_t)E * 4);
    unsigned* hs     = (unsigned*)carve((size_t)N * H * 2);   // bf16 packed
    // region R: early scratch, later aggz (bf16, N*H*2)
    char*     R      = (char*)carve((size_t)N * H * 2);
    uint4*    xp     = (uint4*)   (R);                        // N*16 B
    float*    aggx   = (float*)   (R + (2u << 20));           // N*32 B
    unsigned* pairs  = (unsigned*)(R + (6u << 20));           // E*4 B
    int*      bcnt   = (int*)     (R + (14u << 20));
    int*      bbase  = (int*)     (R + (14u << 20) + 4096);
    int*      cursor = (int*)     (R + (14u << 20) + 8192);
    uint4*    aggz   = (uint4*)R;
    // small tail
    float* pmean = (float*)carve((size_t)G * H * 4);
    int*   pcnt  = (int*)  carve((size_t)G * 4);

    // CSR build (counting sort, all-coalesced writes)
    hipMemsetAsync(bcnt, 0, (size_t)NB * 4, stream);
    bucketA_kernel<<<(E + 4095) / 4096, 256, 0, stream>>>(ei, E, NB, bcnt);
    scan_buckets<<<1, 256, 0, stream>>>(bcnt, NB, E, bbase, cursor);
    bucketB_kernel<<<(E + TS - 1) / TS, 256, 0, stream>>>(ei, E, cursor, pairs);
    group_kernel<<<NB, 256, 0, stream>>>(pairs, bbase, N, NB, E, dis, rowptr, csr);

    // layer 1
    prep_kernel<<<(N + 255) / 256, 256, 0, stream>>>(dis, x, xp, N);
    aggx_kernel<<<(N + 255) / 256, 256, 0, stream>>>(rowptr, csr, dis, xp, aggx, N);
    mm1relu_kernel<<<((size_t)N * 64 + 255) / 256, 256, 0, stream>>>(aggx, W1, b1, dis, hs, N);

    // layer 2 aggregation (bf16 gather) -> aggz (overwrites R)
    aggz_kernel<<<(N + 15) / 16, 256, 0, stream>>>(rowptr, csr, dis, (const uint4*)hs, aggz, N);

    // pool + final GEMM
    pool_kernel<<<(G + 7) / 8, 256, 0, stream>>>((const uint2*)aggz, bat, pmean, pcnt, N, G);
    out_kernel<<<(G + 7) / 8, 128, 0, stream>>>(pmean, pcnt, W2, b2, out, G);
}